// Round 1
// baseline (467.332 us; speedup 1.0000x reference)
//
#include <hip/hip_runtime.h>
#include <stdint.h>

// Problem constants: B=4, N=4096, E=128, H=8, D=16, FF=512
// Heads never mix across the E axis -> treat everything as [B*N, 128].

typedef __attribute__((ext_vector_type(8))) short short8;   // 8 bf16 (4 VGPRs)
typedef __attribute__((ext_vector_type(4))) float f32x4;

__device__ __forceinline__ uint16_t f2bf(float f) {
    uint32_t u = __builtin_bit_cast(uint32_t, f);
    u += 0x7fffu + ((u >> 16) & 1u);   // RNE
    return (uint16_t)(u >> 16);
}
__device__ __forceinline__ float bf2f(uint16_t h) {
    uint32_t u = ((uint32_t)h) << 16;
    return __builtin_bit_cast(float, u);
}
__device__ __forceinline__ f32x4 mfma16(short8 a, short8 b, f32x4 c) {
    return __builtin_amdgcn_mfma_f32_16x16x32_bf16(a, b, c, 0, 0, 0);
}

// ---------------------------------------------------------------- k_prep
// Convert + transpose all weight matrices to bf16, B-operand layout [n][k].
__global__ __launch_bounds__(256) void k_prep(
    const float* __restrict__ Wq, const float* __restrict__ Wk,
    const float* __restrict__ Wv, const float* __restrict__ Wo,
    const float* __restrict__ W1, const float* __restrict__ W2,
    uint16_t* __restrict__ wqkvT, uint16_t* __restrict__ woT,
    uint16_t* __restrict__ w1T, uint16_t* __restrict__ w2T) {
    int t = blockIdx.x * 256 + threadIdx.x;
    if (t < 49152) {                       // wqkvT[n][k], n in [0,384)
        int n = t >> 7, k = t & 127;
        const float* W = (n < 128) ? Wq : (n < 256) ? Wk : Wv;
        wqkvT[t] = f2bf(W[k * 128 + (n & 127)]);
    } else if (t < 65536) {                // woT[e][d] = Wo[d][e]
        int i = t - 49152; int e = i >> 7, d = i & 127;
        woT[i] = f2bf(Wo[d * 128 + e]);
    } else if (t < 131072) {               // w1T[f][e] = W1[e][f]
        int i = t - 65536; int f = i >> 7, e = i & 127;
        w1T[i] = f2bf(W1[e * 512 + f]);
    } else if (t < 196608) {               // w2T[e][f] = W2[f][e]
        int i = t - 131072; int e = i >> 9, f = i & 511;
        w2T[i] = f2bf(W2[f * 128 + e]);
    }
}

// ---------------------------------------------------------------- k_rms
// One wave per row of 128; out = bf16(x * rsqrt(mean(x^2)+eps) * g).
__global__ __launch_bounds__(256) void k_rms(
    const float* __restrict__ x, const float* __restrict__ g,
    uint16_t* __restrict__ o) {
    int row = blockIdx.x * 4 + (threadIdx.x >> 6);
    int l = threadIdx.x & 63;
    float2 v = *(const float2*)(x + (size_t)row * 128 + l * 2);
    float ss = v.x * v.x + v.y * v.y;
    #pragma unroll
    for (int m = 32; m >= 1; m >>= 1) ss += __shfl_xor(ss, m, 64);
    float rs = rsqrtf(ss * (1.0f / 128.0f) + 1e-6f);
    float2 gv = *(const float2*)(g + l * 2);
    uint32_t lo = (uint32_t)f2bf(v.x * rs * gv.x) |
                  ((uint32_t)f2bf(v.y * rs * gv.y) << 16);
    *(uint32_t*)(o + (size_t)row * 128 + l * 2) = lo;
}

// ---------------------------------------------------------------- k_qkv
// [64 x 128] h-tile @ [128 x 384] Wqkv. 6 waves, each 64x64.
// Epilogue: sigq = sigmoid(q) (bf16), McatT[b][col][i] = [exp(k)*v | exp(k)].
__global__ __launch_bounds__(384) void k_qkv(
    const uint16_t* __restrict__ h, const uint16_t* __restrict__ wqkvT,
    uint16_t* __restrict__ sigq, uint16_t* __restrict__ mcatT) {
    __shared__ __align__(16) char sm[65536];
    uint16_t* Al = (uint16_t*)sm;   // 64 x 136 bf16 (17,408 B)
    float*    Pl = (float*)sm;      // 64 x 256 f32  (65,536 B), after K-loop
    const int t = threadIdx.x;
    const int i0 = blockIdx.x * 64;
    for (int idx = t; idx < 1024; idx += 384) {
        int row = idx >> 4, c8 = (idx & 15) * 8;
        *(uint4*)&Al[row * 136 + c8] =
            *(const uint4*)(h + (size_t)(i0 + row) * 128 + c8);
    }
    __syncthreads();
    const int w = t >> 6, l = t & 63, ml = l & 15, qd = l >> 4;
    f32x4 acc[4][4];
    f32x4 zv = {0.f, 0.f, 0.f, 0.f};
    #pragma unroll
    for (int a = 0; a < 4; ++a)
        #pragma unroll
        for (int b = 0; b < 4; ++b) acc[a][b] = zv;
    #pragma unroll
    for (int kc = 0; kc < 4; ++kc) {
        short8 af[4], bfr[4];
        #pragma unroll
        for (int fm = 0; fm < 4; ++fm)
            af[fm] = *(const short8*)&Al[(fm * 16 + ml) * 136 + kc * 32 + qd * 8];
        #pragma unroll
        for (int fn = 0; fn < 4; ++fn)   // B-frags straight from L2 (98 KB matrix)
            bfr[fn] = *(const short8*)(wqkvT + (w * 64 + fn * 16 + ml) * 128 + kc * 32 + qd * 8);
        #pragma unroll
        for (int fm = 0; fm < 4; ++fm)
            #pragma unroll
            for (int fn = 0; fn < 4; ++fn)
                acc[fm][fn] = mfma16(af[fm], bfr[fn], acc[fm][fn]);
    }
    __syncthreads();   // done reading Al; Pl may overwrite
    const int bb = i0 >> 12, il0 = i0 & 4095;
    if (w < 2) {       // q columns -> sigmoid, straight to global
        #pragma unroll
        for (int fm = 0; fm < 4; ++fm)
            #pragma unroll
            for (int fn = 0; fn < 4; ++fn)
                #pragma unroll
                for (int r = 0; r < 4; ++r) {
                    int row = fm * 16 + qd * 4 + r;
                    int col = w * 64 + fn * 16 + ml;
                    sigq[(size_t)(i0 + row) * 128 + col] =
                        f2bf(1.f / (1.f + __expf(-acc[fm][fn][r])));
                }
    } else {           // k -> exp(k) at Pl cols [0,128); v raw at [128,256)
        int half = (w < 4) ? 0 : 1;
        int cbase = (w - (half ? 4 : 2)) * 64;
        #pragma unroll
        for (int fm = 0; fm < 4; ++fm)
            #pragma unroll
            for (int fn = 0; fn < 4; ++fn)
                #pragma unroll
                for (int r = 0; r < 4; ++r) {
                    int row = fm * 16 + qd * 4 + r;
                    int col = cbase + fn * 16 + ml;
                    float vv = acc[fm][fn][r];
                    if (!half) vv = __expf(vv);
                    // column rotation by row to kill bank conflicts on read
                    Pl[row * 256 + half * 128 + ((col + row) & 127)] = vv;
                }
    }
    __syncthreads();
    // McatT[b][c][i]: c<128 -> exp(k)*v ; c>=128 -> exp(k)
    for (int idx = t; idx < 16384; idx += 384) {
        int cc = idx >> 6, il = idx & 63;
        int pc = ((cc & 127) + il) & 127;
        float ekw = Pl[il * 256 + pc];
        float val = (cc < 128) ? ekw * Pl[il * 256 + 128 + pc] : ekw;
        mcatT[((size_t)bb * 256 + cc) * 4096 + il0 + il] = f2bf(val);
    }
}

// ---------------------------------------------------------------- k_big
// Per (jtile, batch, split): C[128 j, 256 col] = sum_i exp(c*dis[i][j]) * Mcat[i][col]
// A (dis_w^T) is built by exp+transpose into LDS each BK=64 step.
__global__ __launch_bounds__(512) void k_big(
    const float* __restrict__ dis, const uint16_t* __restrict__ mcatT,
    const float* __restrict__ alpha_p, float* __restrict__ wbuf) {
    __shared__ __align__(16) uint16_t Al[128 * 72];  // [j][i], pitch 72
    __shared__ __align__(16) uint16_t Bl[256 * 72];  // [col][i], pitch 72
    const int t = threadIdx.x;
    const int j0 = blockIdx.x * 128;
    const int b  = blockIdx.y;
    const int sp = blockIdx.z;
    const float c = -12.0f * alpha_p[0];             // log2(4096)=12
    const int w = t >> 6, l = t & 63, ml = l & 15, qd = l >> 4;
    const int wm = w >> 2, wn = w & 3;
    const int sj4 = (t & 31) * 4, si0 = (t >> 5) * 4;
    const float* disb = dis + (size_t)b * 4096 * 4096;
    const uint16_t* mb = mcatT + (size_t)b * 256 * 4096;

    f32x4 acc[4][4];
    f32x4 zv = {0.f, 0.f, 0.f, 0.f};
    #pragma unroll
    for (int a = 0; a < 4; ++a)
        #pragma unroll
        for (int q = 0; q < 4; ++q) acc[a][q] = zv;

    for (int ks = 0; ks < 32; ++ks) {
        const int ig = sp * 2048 + ks * 64;
        float dv[4][4];
        #pragma unroll
        for (int r = 0; r < 4; ++r) {
            float4 v = *(const float4*)(disb + (size_t)(ig + si0 + r) * 4096 + j0 + sj4);
            dv[r][0] = v.x; dv[r][1] = v.y; dv[r][2] = v.z; dv[r][3] = v.w;
        }
        __syncthreads();   // previous compute done; LDS writable
        #pragma unroll
        for (int jj = 0; jj < 4; ++jj) {   // transpose 4x4 micro-block
            uint32_t lo = (uint32_t)f2bf(__expf(c * dv[0][jj])) |
                          ((uint32_t)f2bf(__expf(c * dv[1][jj])) << 16);
            uint32_t hi = (uint32_t)f2bf(__expf(c * dv[2][jj])) |
                          ((uint32_t)f2bf(__expf(c * dv[3][jj])) << 16);
            uint2 pk = {lo, hi};
            *(uint2*)&Al[(sj4 + jj) * 72 + si0] = pk;
        }
        #pragma unroll
        for (int ii = 0; ii < 4; ++ii) {   // B: straight copy, McatT is pre-transposed
            int idx = t + ii * 512;
            int row = idx >> 3, c8 = (idx & 7) * 8;
            *(uint4*)&Bl[row * 72 + c8] =
                *(const uint4*)(mb + (size_t)row * 4096 + ig + c8);
        }
        __syncthreads();
        #pragma unroll
        for (int kc = 0; kc < 2; ++kc) {
            short8 af[4], bfr[4];
            #pragma unroll
            for (int fm = 0; fm < 4; ++fm)
                af[fm] = *(const short8*)&Al[(wm * 64 + fm * 16 + ml) * 72 + kc * 32 + qd * 8];
            #pragma unroll
            for (int fn = 0; fn < 4; ++fn)
                bfr[fn] = *(const short8*)&Bl[(wn * 64 + fn * 16 + ml) * 72 + kc * 32 + qd * 8];
            #pragma unroll
            for (int fm = 0; fm < 4; ++fm)
                #pragma unroll
                for (int fn = 0; fn < 4; ++fn)
                    acc[fm][fn] = mfma16(af[fm], bfr[fn], acc[fm][fn]);
        }
    }
    float* ob = wbuf + ((size_t)(sp * 4 + b) * 4096 + j0) * 256;
    #pragma unroll
    for (int fm = 0; fm < 4; ++fm)
        #pragma unroll
        for (int fn = 0; fn < 4; ++fn) {
            int col = wn * 64 + fn * 16 + ml;
            #pragma unroll
            for (int r = 0; r < 4; ++r) {
                int rowl = wm * 64 + fm * 16 + qd * 4 + r;
                ob[(size_t)rowl * 256 + col] = acc[fm][fn][r];
            }
        }
}

// ---------------------------------------------------------------- k_att
// att = sigq * (w1/w2) (merging split-K halves), out1 = x + att @ Wo.
__global__ __launch_bounds__(256) void k_att(
    const float* __restrict__ wbuf, const uint16_t* __restrict__ sigq,
    const uint16_t* __restrict__ woT, const float* __restrict__ x,
    float* __restrict__ out1) {
    __shared__ __align__(16) uint16_t Al[64 * 136];
    __shared__ __align__(16) uint16_t Bl[128 * 136];
    const int t = threadIdx.x;
    const int i0 = blockIdx.x * 64;
    const int b = i0 >> 12, jl0 = i0 & 4095;
    const float* wb0 = wbuf + ((size_t)b * 4096 + jl0) * 256;
    const float* wb1 = wbuf + ((size_t)(4 + b) * 4096 + jl0) * 256;
    #pragma unroll
    for (int ii = 0; ii < 8; ++ii) {
        int idx = t + ii * 256;
        int row = idx >> 5, c4 = (idx & 31) * 4;
        float4 a0 = *(const float4*)(wb0 + (size_t)row * 256 + c4);
        float4 a1 = *(const float4*)(wb1 + (size_t)row * 256 + c4);
        float4 d0 = *(const float4*)(wb0 + (size_t)row * 256 + 128 + c4);
        float4 d1 = *(const float4*)(wb1 + (size_t)row * 256 + 128 + c4);
        const uint16_t* sq = sigq + (size_t)(i0 + row) * 128 + c4;
        uint32_t lo = (uint32_t)f2bf(bf2f(sq[0]) * (a0.x + a1.x) / (d0.x + d1.x)) |
                      ((uint32_t)f2bf(bf2f(sq[1]) * (a0.y + a1.y) / (d0.y + d1.y)) << 16);
        uint32_t hi = (uint32_t)f2bf(bf2f(sq[2]) * (a0.z + a1.z) / (d0.z + d1.z)) |
                      ((uint32_t)f2bf(bf2f(sq[3]) * (a0.w + a1.w) / (d0.w + d1.w)) << 16);
        uint2 pk = {lo, hi};
        *(uint2*)&Al[row * 136 + c4] = pk;
    }
    #pragma unroll
    for (int ii = 0; ii < 8; ++ii) {
        int idx = t + ii * 256;
        int row = idx >> 4, c8 = (idx & 15) * 8;
        *(uint4*)&Bl[row * 136 + c8] = *(const uint4*)(woT + row * 128 + c8);
    }
    __syncthreads();
    const int w = t >> 6, l = t & 63, ml = l & 15, qd = l >> 4;
    const int wm = w >> 1, wn = w & 1;
    f32x4 acc[2][4];
    f32x4 zv = {0.f, 0.f, 0.f, 0.f};
    #pragma unroll
    for (int a = 0; a < 2; ++a)
        #pragma unroll
        for (int q = 0; q < 4; ++q) acc[a][q] = zv;
    #pragma unroll
    for (int kc = 0; kc < 4; ++kc) {
        short8 af[2], bfr[4];
        #pragma unroll
        for (int fm = 0; fm < 2; ++fm)
            af[fm] = *(const short8*)&Al[(wm * 32 + fm * 16 + ml) * 136 + kc * 32 + qd * 8];
        #pragma unroll
        for (int fn = 0; fn < 4; ++fn)
            bfr[fn] = *(const short8*)&Bl[(wn * 64 + fn * 16 + ml) * 136 + kc * 32 + qd * 8];
        #pragma unroll
        for (int fm = 0; fm < 2; ++fm)
            #pragma unroll
            for (int fn = 0; fn < 4; ++fn)
                acc[fm][fn] = mfma16(af[fm], bfr[fn], acc[fm][fn]);
    }
    #pragma unroll
    for (int fm = 0; fm < 2; ++fm)
        #pragma unroll
        for (int fn = 0; fn < 4; ++fn) {
            int col = wn * 64 + fn * 16 + ml;
            #pragma unroll
            for (int r = 0; r < 4; ++r) {
                int rowl = wm * 32 + fm * 16 + qd * 4 + r;
                size_t o = (size_t)(i0 + rowl) * 128 + col;
                out1[o] = x[o] + acc[fm][fn][r];
            }
        }
}

// ---------------------------------------------------------------- k_ff1
// R = relu(h2 @ W1 + b1), tile 64 x 128, grid (256, 4).
__global__ __launch_bounds__(256) void k_ff1(
    const uint16_t* __restrict__ h2, const uint16_t* __restrict__ w1T,
    const float* __restrict__ b1, uint16_t* __restrict__ R) {
    __shared__ __align__(16) uint16_t Al[64 * 136];
    __shared__ __align__(16) uint16_t Bl[128 * 136];
    const int t = threadIdx.x;
    const int i0 = blockIdx.x * 64;
    const int nt = blockIdx.y;
    #pragma unroll
    for (int ii = 0; ii < 4; ++ii) {
        int idx = t + ii * 256;
        int row = idx >> 4, c8 = (idx & 15) * 8;
        *(uint4*)&Al[row * 136 + c8] =
            *(const uint4*)(h2 + (size_t)(i0 + row) * 128 + c8);
    }
    #pragma unroll
    for (int ii = 0; ii < 8; ++ii) {
        int idx = t + ii * 256;
        int row = idx >> 4, c8 = (idx & 15) * 8;
        *(uint4*)&Bl[row * 136 + c8] =
            *(const uint4*)(w1T + (size_t)(nt * 128 + row) * 128 + c8);
    }
    __syncthreads();
    const int w = t >> 6, l = t & 63, ml = l & 15, qd = l >> 4;
    const int wm = w >> 1, wn = w & 1;
    f32x4 acc[2][4];
    f32x4 zv = {0.f, 0.f, 0.f, 0.f};
    #pragma unroll
    for (int a = 0; a < 2; ++a)
        #pragma unroll
        for (int q = 0; q < 4; ++q) acc[a][q] = zv;
    #pragma unroll
    for (int kc = 0; kc < 4; ++kc) {
        short8 af[2], bfr[4];
        #pragma unroll
        for (int fm = 0; fm < 2; ++fm)
            af[fm] = *(const short8*)&Al[(wm * 32 + fm * 16 + ml) * 136 + kc * 32 + qd * 8];
        #pragma unroll
        for (int fn = 0; fn < 4; ++fn)
            bfr[fn] = *(const short8*)&Bl[(wn * 64 + fn * 16 + ml) * 136 + kc * 32 + qd * 8];
        #pragma unroll
        for (int fm = 0; fm < 2; ++fm)
            #pragma unroll
            for (int fn = 0; fn < 4; ++fn)
                acc[fm][fn] = mfma16(af[fm], bfr[fn], acc[fm][fn]);
    }
    #pragma unroll
    for (int fm = 0; fm < 2; ++fm)
        #pragma unroll
        for (int fn = 0; fn < 4; ++fn) {
            int col = wn * 64 + fn * 16 + ml;
            int gcol = nt * 128 + col;
            #pragma unroll
            for (int r = 0; r < 4; ++r) {
                int rowl = wm * 32 + fm * 16 + qd * 4 + r;
                R[(size_t)(i0 + rowl) * 512 + gcol] =
                    f2bf(fmaxf(acc[fm][fn][r] + b1[gcol], 0.f));
            }
        }
}

// ---------------------------------------------------------------- k_ff2
// out = out1 + (R @ W2 + b2). K=512 in 4 chunks of 128.
__global__ __launch_bounds__(256) void k_ff2(
    const uint16_t* __restrict__ Rm, const uint16_t* __restrict__ w2T,
    const float* __restrict__ b2, const float* __restrict__ out1,
    float* __restrict__ out) {
    __shared__ __align__(16) uint16_t Al[64 * 136];
    __shared__ __align__(16) uint16_t Bl[128 * 136];
    const int t = threadIdx.x;
    const int i0 = blockIdx.x * 64;
    const int w = t >> 6, l = t & 63, ml = l & 15, qd = l >> 4;
    const int wm = w >> 1, wn = w & 1;
    f32x4 acc[2][4];
    f32x4 zv = {0.f, 0.f, 0.f, 0.f};
    #pragma unroll
    for (int a = 0; a < 2; ++a)
        #pragma unroll
        for (int q = 0; q < 4; ++q) acc[a][q] = zv;
    for (int kb = 0; kb < 4; ++kb) {
        __syncthreads();
        #pragma unroll
        for (int ii = 0; ii < 4; ++ii) {
            int idx = t + ii * 256;
            int row = idx >> 4, c8 = (idx & 15) * 8;
            *(uint4*)&Al[row * 136 + c8] =
                *(const uint4*)(Rm + (size_t)(i0 + row) * 512 + kb * 128 + c8);
        }
        #pragma unroll
        for (int ii = 0; ii < 8; ++ii) {
            int idx = t + ii * 256;
            int row = idx >> 4, c8 = (idx & 15) * 8;
            *(uint4*)&Bl[row * 136 + c8] =
                *(const uint4*)(w2T + (size_t)row * 512 + kb * 128 + c8);
        }
        __syncthreads();
        #pragma unroll
        for (int kc = 0; kc < 4; ++kc) {
            short8 af[2], bfr[4];
            #pragma unroll
            for (int fm = 0; fm < 2; ++fm)
                af[fm] = *(const short8*)&Al[(wm * 32 + fm * 16 + ml) * 136 + kc * 32 + qd * 8];
            #pragma unroll
            for (int fn = 0; fn < 4; ++fn)
                bfr[fn] = *(const short8*)&Bl[(wn * 64 + fn * 16 + ml) * 136 + kc * 32 + qd * 8];
            #pragma unroll
            for (int fm = 0; fm < 2; ++fm)
                #pragma unroll
                for (int fn = 0; fn < 4; ++fn)
                    acc[fm][fn] = mfma16(af[fm], bfr[fn], acc[fm][fn]);
        }
    }
    #pragma unroll
    for (int fm = 0; fm < 2; ++fm)
        #pragma unroll
        for (int fn = 0; fn < 4; ++fn) {
            int col = wn * 64 + fn * 16 + ml;
            #pragma unroll
            for (int r = 0; r < 4; ++r) {
                int rowl = wm * 32 + fm * 16 + qd * 4 + r;
                size_t o = (size_t)(i0 + rowl) * 128 + col;
                out[o] = out1[o] + b2[col] + acc[fm][fn][r];
            }
        }
}

// ---------------------------------------------------------------- launch
extern "C" void kernel_launch(void* const* d_in, const int* in_sizes, int n_in,
                              void* d_out, int out_size, void* d_ws, size_t ws_size,
                              hipStream_t stream) {
    (void)in_sizes; (void)n_in; (void)out_size; (void)ws_size;
    const float* x      = (const float*)d_in[0];
    const float* dis    = (const float*)d_in[1];
    const float* g_in   = (const float*)d_in[2];
    const float* g_post = (const float*)d_in[3];
    const float* Wq     = (const float*)d_in[4];
    const float* Wk     = (const float*)d_in[5];
    const float* Wv     = (const float*)d_in[6];
    const float* alpha  = (const float*)d_in[7];
    const float* Wo     = (const float*)d_in[8];
    const float* W1     = (const float*)d_in[9];
    const float* b1     = (const float*)d_in[10];
    const float* W2     = (const float*)d_in[11];
    const float* b2     = (const float*)d_in[12];
    float* out = (float*)d_out;

    char* ws = (char*)d_ws;
    size_t off = 0;
    auto take = [&](size_t bytes) -> char* {
        char* p = ws + off;
        off += (bytes + 255) & ~(size_t)255;
        return p;
    };
    uint16_t* h     = (uint16_t*)take(16384ull * 128 * 2);     //  4 MB
    uint16_t* wqkvT = (uint16_t*)take(384ull * 128 * 2);
    uint16_t* woT   = (uint16_t*)take(128ull * 128 * 2);
    uint16_t* w1T   = (uint16_t*)take(512ull * 128 * 2);
    uint16_t* w2T   = (uint16_t*)take(128ull * 512 * 2);
    uint16_t* sigq  = (uint16_t*)take(16384ull * 128 * 2);     //  4 MB
    uint16_t* mcatT = (uint16_t*)take(4ull * 256 * 4096 * 2);  //  8 MB
    float*    wbuf  = (float*)take(2ull * 4 * 4096 * 256 * 4); // 33.5 MB
    float*    out1  = (float*)take(16384ull * 128 * 4);        //  8 MB
    uint16_t* h2    = (uint16_t*)take(16384ull * 128 * 2);     //  4 MB
    uint16_t* R     = (uint16_t*)take(16384ull * 512 * 2);     // 16 MB

    k_prep<<<768, 256, 0, stream>>>(Wq, Wk, Wv, Wo, W1, W2, wqkvT, woT, w1T, w2T);
    k_rms<<<4096, 256, 0, stream>>>(x, g_in, h);
    k_qkv<<<256, 384, 0, stream>>>(h, wqkvT, sigq, mcatT);
    k_big<<<dim3(32, 4, 2), 512, 0, stream>>>(dis, mcatT, alpha, wbuf);
    k_att<<<256, 256, 0, stream>>>(wbuf, sigq, woT, x, out1);
    k_rms<<<4096, 256, 0, stream>>>(out1, g_post, h2);
    k_ff1<<<dim3(256, 4), 256, 0, stream>>>(h2, w1T, b1, R);
    k_ff2<<<256, 256, 0, stream>>>(R, w2T, b2, out1, out);
}